// Round 11
// baseline (568.564 us; speedup 1.0000x reference)
//
#include <hip/hip_runtime.h>
#include <hip/hip_bf16.h>
#include <math.h>

#define Bsz 16384
#define HIDc 1024

typedef __attribute__((ext_vector_type(8))) short short8_t;
typedef __attribute__((ext_vector_type(16))) float f32x16;
typedef __attribute__((ext_vector_type(4))) short s16x4;

typedef __attribute__((address_space(1))) const unsigned char* gp1_t;
typedef __attribute__((address_space(3))) unsigned char* lp3_t;

__device__ __forceinline__ float sigf(float x) { return 1.0f / (1.0f + __expf(-x)); }
__device__ __forceinline__ float tanh_fast(float x) {
  x = fminf(fmaxf(x, -10.f), 10.f);
  float t = __expf(2.f * x);
  return (t - 1.f) / (t + 1.f);
}

// Bijective XCD-chunked swizzle (T1, m204 form). r2 evidence: final FETCH
// 573 MB -> 280 MB. Keep everywhere.
__device__ __forceinline__ int xcd_map(int bid, int nwg) {
  const int q = nwg >> 3, r = nwg & 7;
  const int xcd = bid & 7, idx = bid >> 3;
  return (xcd < r ? xcd * (q + 1) : r * (q + 1) + (xcd - r) * q) + idx;
}

// Stage a 128x64 bf16 tile (16 KB) into LDS with global_load_lds width=16.
// LDS dest linear; k-slot XOR swizzle applied on the GLOBAL source address
// (both-sides-or-neither, rule #21): phys slot p of row r holds logical p^(r&7).
__device__ __forceinline__ void stage64(const __hip_bfloat16* __restrict__ g, long ld,
                                        __hip_bfloat16* l, int wave, int lane) {
  const int rsub = lane >> 3;                    // row within 8-row chunk
  const int kx = ((lane & 7) ^ rsub) << 3;       // swizzled source col (elems)
#pragma unroll
  for (int i = 0; i < 4; ++i) {
    const int chunk = i * 4 + wave;              // 0..15, 8 rows each
    const int row = chunk * 8 + rsub;
    const __hip_bfloat16* gp = g + (long)row * ld + kx;
    __hip_bfloat16* lp = l + chunk * 512 + lane * 8;   // chunk*1024B + lane*16B
    __builtin_amdgcn_global_load_lds((gp1_t)gp, (lp3_t)lp, 16, 0, 0);
  }
}

// Serial m97-style K-loop, 32x32x16 MFMA variant (r11). Same proven 2-barrier
// schedule, staging, and LDS layout as r4-r10; only the fragment shape changes:
// 32x32 runs 4060 FLOP/CU-cyc vs 16x16's 3378 (m119) and halves MFMA count.
// A/B frag: lane l -> row l&31, k = (l>>5)*8..+8 (contiguous-8, gfx950 2xK).
__device__ __forceinline__ void gemm_acc(const __hip_bfloat16* __restrict__ A, long lda,
                                         const __hip_bfloat16* __restrict__ Wt, long ldw,
                                         int K,
                                         __hip_bfloat16* lA, __hip_bfloat16* lB,
                                         f32x16 acc[2][2]) {
  const int tid = threadIdx.x;
  const int wave = tid >> 6, lane = tid & 63;
  const int wr = wave >> 1, wc = wave & 1;
  const int lm32 = lane & 31, hi2 = lane >> 5, l7 = lane & 7;
  for (int k0 = 0; k0 < K; k0 += 64) {
    __syncthreads();                       // previous compute done before overwrite
    stage64(A + k0, lda, lA, wave, lane);
    stage64(Wt + k0, ldw, lB, wave, lane);
    __syncthreads();                       // compiler drains vmcnt before barrier
#pragma unroll
    for (int t = 0; t < 4; ++t) {          // K=16 per MFMA, 4 per K-step
      const int sl = t * 2 + hi2;          // logical 16B slot 0..7
      short8_t a8[2], b8[2];
#pragma unroll
      for (int fm = 0; fm < 2; ++fm) {
        const int r = wr * 64 + fm * 32 + lm32;
        a8[fm] = *reinterpret_cast<const short8_t*>(lA + r * 64 + ((sl ^ l7) << 3));
      }
#pragma unroll
      for (int fn = 0; fn < 2; ++fn) {
        const int r = wc * 64 + fn * 32 + lm32;
        b8[fn] = *reinterpret_cast<const short8_t*>(lB + r * 64 + ((sl ^ l7) << 3));
      }
#pragma unroll
      for (int fm = 0; fm < 2; ++fm)
#pragma unroll
        for (int fn = 0; fn < 2; ++fn)
          acc[fm][fn] = __builtin_amdgcn_mfma_f32_32x32x16_bf16(a8[fm], b8[fn],
                                                                acc[fm][fn], 0, 0, 0);
    }
  }
}

// C/D layout (32x32, m74/m101 HW-verified): col = lane&31,
// row = (reg&3) + 8*(reg>>2) + 4*(lane>>5).
// mega_k: G1+G2+G3 in one dispatch.
//   [0,2048):    G1  [x|state]@[Wr|Wu], K=2048 -> rs=sig(v+br)*st, u=sig(v+bu)
//   [2048,4096): G2  x@[W1|Wc_top],     K=1024 -> sem=relu(v+b1)->SN, cx=v+bc
//   [4096,5120): G3  neighbors@W2,      K=1024 -> nei=relu(v+b2)->SN+1024
__global__ void mega_k(const __hip_bfloat16* __restrict__ A1,
                       const __hip_bfloat16* __restrict__ NB,
                       const __hip_bfloat16* __restrict__ Wru,
                       const __hip_bfloat16* __restrict__ W1cx,
                       const __hip_bfloat16* __restrict__ W2t,
                       const float* __restrict__ br, const float* __restrict__ bu,
                       const float* __restrict__ b1, const float* __restrict__ bc,
                       const float* __restrict__ b2,
                       __hip_bfloat16* __restrict__ RS, __hip_bfloat16* __restrict__ Ub,
                       __hip_bfloat16* __restrict__ SN, __hip_bfloat16* __restrict__ CXb) {
  __shared__ __hip_bfloat16 lA[128 * 64], lB[128 * 64];
  const int bid = blockIdx.x;
  const __hip_bfloat16 *A, *Wt;
  long lda, ldw;
  int K, nbx, epi, local, seg;
  if (bid < 2048)      { local = bid;        seg = 2048; epi = 0; A = A1; lda = 2048; Wt = Wru;  ldw = 2048; K = 2048; nbx = 16; }
  else if (bid < 4096) { local = bid - 2048; seg = 2048; epi = 1; A = A1; lda = 2048; Wt = W1cx; ldw = 1024; K = 1024; nbx = 16; }
  else                 { local = bid - 4096; seg = 1024; epi = 2; A = NB; lda = 1024; Wt = W2t;  ldw = 1024; K = 1024; nbx = 8;  }
  const int wg = xcd_map(local, seg);
  const long mBase = (long)(wg / nbx) * 128;
  const long nBase = (long)(wg % nbx) * 128;

  f32x16 acc[2][2];
#pragma unroll
  for (int m = 0; m < 2; ++m)
#pragma unroll
    for (int n = 0; n < 2; ++n)
#pragma unroll
      for (int j = 0; j < 16; ++j) acc[m][n][j] = 0.f;

  gemm_acc(A + mBase * lda, lda, Wt + nBase * ldw, ldw, K, lA, lB, acc);

  const int tid = threadIdx.x, wave = tid >> 6, lane = tid & 63;
  const int wr = wave >> 1, wc = wave & 1, lm32 = lane & 31, hi2 = lane >> 5;
  const int row0 = (int)mBase + wr * 64 + hi2 * 4;
  const int col0 = (int)nBase + wc * 64 + lm32;
#pragma unroll
  for (int fm = 0; fm < 2; ++fm)
#pragma unroll
    for (int fn = 0; fn < 2; ++fn)
#pragma unroll
      for (int j = 0; j < 16; ++j) {
        const long row = row0 + fm * 32 + (j & 3) + 8 * (j >> 2);
        const int col = col0 + fn * 32;
        const float v = acc[fm][fn][j];
        if (epi == 0) {
          if (col < HIDc) {
            float rr = sigf(v + br[col]);
            float st = __bfloat162float(A1[row * 2048 + 1024 + col]);
            RS[row * HIDc + col] = __float2bfloat16(rr * st);
          } else {
            int c = col - HIDc;
            Ub[row * HIDc + c] = __float2bfloat16(sigf(v + bu[c]));
          }
        } else if (epi == 1) {
          if (col < HIDc) {
            SN[row * 2048 + col] = __float2bfloat16(fmaxf(v + b1[col], 0.f));
          } else {
            int c = col - HIDc;
            CXb[row * HIDc + c] = __float2bfloat16(v + bc[c]);
          }
        } else {
          SN[row * 2048 + HIDc + col] = __float2bfloat16(fmaxf(v + b2[col], 0.f));
        }
      }
}

// final_c: cb = tanh(cx + rs @ Wc_bot^T) -> CB (bf16).
__global__ void final_c(const __hip_bfloat16* __restrict__ A, long lda,
                        const __hip_bfloat16* __restrict__ Wt, long ldw, int K, int nbx,
                        const __hip_bfloat16* __restrict__ auxbf,  // CXb (ld 1024)
                        __hip_bfloat16* __restrict__ out0) {
  __shared__ __hip_bfloat16 lA[128 * 64], lB[128 * 64];
  f32x16 acc[2][2];
#pragma unroll
  for (int m = 0; m < 2; ++m)
#pragma unroll
    for (int n = 0; n < 2; ++n)
#pragma unroll
      for (int j = 0; j < 16; ++j) acc[m][n][j] = 0.f;

  const int wg = xcd_map(blockIdx.x, gridDim.x);
  const long mBase = (long)(wg / nbx) * 128;
  const long nBase = (long)(wg % nbx) * 128;
  gemm_acc(A + mBase * lda, lda, Wt + nBase * ldw, ldw, K, lA, lB, acc);

  const int tid = threadIdx.x, wave = tid >> 6, lane = tid & 63;
  const int wr = wave >> 1, wc = wave & 1, lm32 = lane & 31, hi2 = lane >> 5;
  const int row0 = (int)mBase + wr * 64 + hi2 * 4;
  const int col0 = (int)nBase + wc * 64 + lm32;
#pragma unroll
  for (int fm = 0; fm < 2; ++fm)
#pragma unroll
    for (int fn = 0; fn < 2; ++fn)
#pragma unroll
      for (int j = 0; j < 16; ++j) {
        const long row = row0 + fm * 32 + (j & 3) + 8 * (j >> 2);
        const int col = col0 + fn * 32;
        const long idx = row * HIDc + col;
        float cb = tanh_fast(acc[fm][fn][j] + __bfloat162float(auxbf[idx]));
        out0[idx] = __float2bfloat16(cb);
      }
}

// final_g: accG = [sem|nei] @ Wg^T (K=2048);
// out = u*state + (1-u)*cb*sigmoid(accG+bg).
__global__ void final_g(const __hip_bfloat16* __restrict__ SN,
                        const __hip_bfloat16* __restrict__ Wgt,
                        const __hip_bfloat16* __restrict__ CB,
                        const __hip_bfloat16* __restrict__ U,
                        const __hip_bfloat16* __restrict__ stbf,  // A1 (state at col 1024+)
                        const float* __restrict__ bg,
                        float* __restrict__ out, int nbx) {
  __shared__ __hip_bfloat16 lA[128 * 64], lB[128 * 64];
  f32x16 acc[2][2];
#pragma unroll
  for (int m = 0; m < 2; ++m)
#pragma unroll
    for (int n = 0; n < 2; ++n)
#pragma unroll
      for (int j = 0; j < 16; ++j) acc[m][n][j] = 0.f;

  const int wg = xcd_map(blockIdx.x, gridDim.x);
  const long mBase = (long)(wg / nbx) * 128;
  const long nBase = (long)(wg % nbx) * 128;
  gemm_acc(SN + mBase * 2048, 2048, Wgt + nBase * 2048, 2048, 2048, lA, lB, acc);

  const int tid = threadIdx.x, wave = tid >> 6, lane = tid & 63;
  const int wr = wave >> 1, wc = wave & 1, lm32 = lane & 31, hi2 = lane >> 5;
  const int row0 = (int)mBase + wr * 64 + hi2 * 4;
  const int col0 = (int)nBase + wc * 64 + lm32;
#pragma unroll
  for (int fm = 0; fm < 2; ++fm)
#pragma unroll
    for (int fn = 0; fn < 2; ++fn)
#pragma unroll
      for (int j = 0; j < 16; ++j) {
        const long row = row0 + fm * 32 + (j & 3) + 8 * (j >> 2);
        const int col = col0 + fn * 32;
        const long idx = row * HIDc + col;
        float g = sigf(acc[fm][fn][j] + bg[col]);
        float u = __bfloat162float(U[idx]);
        float cb = __bfloat162float(CB[idx]);
        float st = __bfloat162float(stbf[row * 2048 + 1024 + col]);
        out[idx] = u * st + (1.f - u) * cb * g;
      }
}

// One prep kernel (proven r7): blocks [0,10240) transpose all 7 weight views
// to (N,K) bf16; blocks [10240,12288) pack activations to bf16.
__global__ __launch_bounds__(256)
void prep_k(const float4* __restrict__ in4, const float4* __restrict__ st4,
            __hip_bfloat16* __restrict__ A1, __hip_bfloat16* __restrict__ NB,
            const float* __restrict__ Wr, const float* __restrict__ Wu,
            const float* __restrict__ W1, const float* __restrict__ Wc,
            const float* __restrict__ W2, const float* __restrict__ Wg,
            __hip_bfloat16* __restrict__ Wru_t, __hip_bfloat16* __restrict__ W1cx_t,
            __hip_bfloat16* __restrict__ Wcb_t, __hip_bfloat16* __restrict__ W2_t,
            __hip_bfloat16* __restrict__ Wg_t) {
  const int bid = blockIdx.x;
  if (bid < 10240) {
    const float* s_; __hip_bfloat16* d_; long ldo; int j, ktiles;
    if (bid < 2048)      { j = bid;        s_ = Wr; d_ = Wru_t;               ldo = 2048; ktiles = 64; }
    else if (bid < 4096) { j = bid - 2048; s_ = Wu; d_ = Wru_t + 1024L * 2048; ldo = 2048; ktiles = 64; }
    else if (bid < 5120) { j = bid - 4096; s_ = W1; d_ = W1cx_t;              ldo = 1024; ktiles = 32; }
    else if (bid < 6144) { j = bid - 5120; s_ = Wc; d_ = W1cx_t + 1024L * 1024; ldo = 1024; ktiles = 32; }
    else if (bid < 7168) { j = bid - 6144; s_ = Wc + 1024L * 1024; d_ = Wcb_t; ldo = 1024; ktiles = 32; }
    else if (bid < 8192) { j = bid - 7168; s_ = W2; d_ = W2_t;                ldo = 1024; ktiles = 32; }
    else                 { j = bid - 8192; s_ = Wg; d_ = Wg_t;                ldo = 2048; ktiles = 64; }
    const int k0 = (j % ktiles) * 32, n0 = (j / ktiles) * 32;
    __shared__ float t[32][33];
    const int tx = threadIdx.x & 31, ty = threadIdx.x >> 5;
#pragma unroll
    for (int dy = 0; dy < 32; dy += 8)
      t[ty + dy][tx] = s_[(long)(k0 + ty + dy) * 1024 + n0 + tx];
    __syncthreads();
#pragma unroll
    for (int dy = 0; dy < 32; dy += 8)
      d_[(long)(n0 + ty + dy) * ldo + k0 + tx] = __float2bfloat16(t[tx][ty + dy]);
  } else {
    const long NI4 = (long)Bsz * 2048 / 4;
    const long NS4 = (long)Bsz * 1024 / 4;
    for (long i = (long)(bid - 10240) * 256 + threadIdx.x; i < NI4 + NS4;
         i += 2048L * 256) {
      float4 v;
      __hip_bfloat16* dst;
      if (i < NI4) {
        v = in4[i];
        long e = i << 2;
        long row = e >> 11;
        int col = (int)(e & 2047);
        dst = (col < 1024) ? (A1 + row * 2048 + col) : (NB + row * 1024 + (col - 1024));
      } else {
        long jj = i - NI4;
        v = st4[jj];
        long e = jj << 2;
        long row = e >> 10;
        int col = (int)(e & 1023);
        dst = A1 + row * 2048 + 1024 + col;
      }
      union { __hip_bfloat16 h[4]; s16x4 s; } u;
      u.h[0] = __float2bfloat16(v.x);
      u.h[1] = __float2bfloat16(v.y);
      u.h[2] = __float2bfloat16(v.z);
      u.h[3] = __float2bfloat16(v.w);
      *reinterpret_cast<s16x4*>(dst) = u.s;
    }
  }
}

extern "C" void kernel_launch(void* const* d_in, const int* in_sizes, int n_in,
                              void* d_out, int out_size, void* d_ws, size_t ws_size,
                              hipStream_t stream) {
  const float* inputs = (const float*)d_in[0];
  const float* state = (const float*)d_in[1];
  const float* Wr = (const float*)d_in[2];
  const float* br = (const float*)d_in[3];
  const float* Wu = (const float*)d_in[4];
  const float* bu = (const float*)d_in[5];
  const float* Wc = (const float*)d_in[6];
  const float* bc = (const float*)d_in[7];
  const float* W1 = (const float*)d_in[8];
  const float* b1 = (const float*)d_in[9];
  const float* W2 = (const float*)d_in[10];
  const float* b2 = (const float*)d_in[11];
  const float* Wg = (const float*)d_in[12];
  const float* bg = (const float*)d_in[13];
  float* out = (float*)d_out;

  char* ws = (char*)d_ws;
  __hip_bfloat16* A1    = (__hip_bfloat16*)(ws);                 // 64 MB [x|state]
  __hip_bfloat16* NB    = (__hip_bfloat16*)(ws + 67108864L);     // 32 MB neighbors -> CB
  __hip_bfloat16* RS    = (__hip_bfloat16*)(ws + 100663296L);    // 32 MB r*state
  __hip_bfloat16* Ub    = (__hip_bfloat16*)(ws + 134217728L);    // 32 MB u
  __hip_bfloat16* SN    = (__hip_bfloat16*)(ws + 167772160L);    // 64 MB [sem|nei]
  __hip_bfloat16* CXb   = (__hip_bfloat16*)(ws + 234881024L);    // 32 MB x@Wc_top+bc
  __hip_bfloat16* Wru_t = (__hip_bfloat16*)(ws + 268435456L);    // 8 MB  (2048 x 2048)
  __hip_bfloat16* W1cx_t= (__hip_bfloat16*)(ws + 276824064L);    // 4 MB  (2048 x 1024)
  __hip_bfloat16* Wcb_t = (__hip_bfloat16*)(ws + 281018368L);    // 2 MB  (1024 x 1024)
  __hip_bfloat16* W2_t  = (__hip_bfloat16*)(ws + 283115520L);    // 2 MB  (1024 x 1024)
  __hip_bfloat16* Wg_t  = (__hip_bfloat16*)(ws + 285212672L);    // 4 MB  (1024 x 2048)
  __hip_bfloat16* CB    = NB;   // NB dead after mega (G3 segment); reuse for tanh(c)

  prep_k<<<12288, 256, 0, stream>>>((const float4*)inputs, (const float4*)state,
                                    A1, NB, Wr, Wu, W1, Wc, W2, Wg,
                                    Wru_t, W1cx_t, Wcb_t, W2_t, Wg_t);

  // G1 + G2 + G3 fused into one dispatch (5120 blocks).
  mega_k<<<5120, 256, 0, stream>>>(A1, NB, Wru_t, W1cx_t, W2_t,
                                   br, bu, b1, bc, b2,
                                   RS, Ub, SN, CXb);

  // final_c: cb = tanh(cx + rs @ Wc_bot^T) -> CB
  final_c<<<1024, 256, 0, stream>>>(RS, 1024, Wcb_t, 1024, 1024, 8, CXb, CB);

  // final_g: out = u*state + (1-u)*cb*sigmoid([sem|nei] @ Wg^T + bg)
  final_g<<<1024, 256, 0, stream>>>(SN, Wg_t, CB, Ub, A1, bg, out, 8);
}

// Round 12
// 510.430 us; speedup vs baseline: 1.1139x; 1.1139x over previous
//
#include <hip/hip_runtime.h>
#include <hip/hip_bf16.h>
#include <math.h>

#define Bsz 16384
#define HIDc 1024

typedef __attribute__((ext_vector_type(8))) short short8_t;
typedef __attribute__((ext_vector_type(4))) float f32x4;
typedef __attribute__((ext_vector_type(4))) short s16x4;

typedef __attribute__((address_space(1))) const unsigned char* gp1_t;
typedef __attribute__((address_space(3))) unsigned char* lp3_t;

__device__ __forceinline__ float sigf(float x) { return 1.0f / (1.0f + __expf(-x)); }
__device__ __forceinline__ float tanh_fast(float x) {
  x = fminf(fmaxf(x, -10.f), 10.f);
  float t = __expf(2.f * x);
  return (t - 1.f) / (t + 1.f);
}

// Bijective XCD-chunked swizzle (T1, m204 form). r2 evidence: final FETCH
// 573 MB -> 280 MB. Keep everywhere.
__device__ __forceinline__ int xcd_map(int bid, int nwg) {
  const int q = nwg >> 3, r = nwg & 7;
  const int xcd = bid & 7, idx = bid >> 3;
  return (xcd < r ? xcd * (q + 1) : r * (q + 1) + (xcd - r) * q) + idx;
}

// Stage a 128x64 bf16 tile (16 KB) into LDS with global_load_lds width=16.
// LDS dest linear; k-slot XOR swizzle applied on the GLOBAL source address
// (both-sides-or-neither, rule #21): phys slot p of row r holds logical p^(r&7).
__device__ __forceinline__ void stage64(const __hip_bfloat16* __restrict__ g, long ld,
                                        __hip_bfloat16* l, int wave, int lane) {
  const int rsub = lane >> 3;                    // row within 8-row chunk
  const int kx = ((lane & 7) ^ rsub) << 3;       // swizzled source col (elems)
#pragma unroll
  for (int i = 0; i < 4; ++i) {
    const int chunk = i * 4 + wave;              // 0..15, 8 rows each
    const int row = chunk * 8 + rsub;
    const __hip_bfloat16* gp = g + (long)row * ld + kx;
    __hip_bfloat16* lp = l + chunk * 512 + lane * 8;   // chunk*1024B + lane*16B
    __builtin_amdgcn_global_load_lds((gp1_t)gp, (lp3_t)lp, 16, 0, 0);
  }
}

// Serial m97-style K-loop (32 KB LDS), 16x16x32 MFMA. Bracketed optimum:
// deeper pipelines (r5-r8), 32x32 shape (r11: 128B row stride => bank =
// f(slot) only => 32 rows/8 slots = 4-way conflict), larger tiles (m105/m112)
// and dual-GEMM fusion (r3 spills) all measured slower. Do not touch.
__device__ __forceinline__ void gemm_acc(const __hip_bfloat16* __restrict__ A, long lda,
                                         const __hip_bfloat16* __restrict__ Wt, long ldw,
                                         int K,
                                         __hip_bfloat16* lA, __hip_bfloat16* lB,
                                         f32x4 acc[4][4]) {
  const int tid = threadIdx.x;
  const int wave = tid >> 6, lane = tid & 63;
  const int wr = wave >> 1, wc = wave & 1;
  const int lm = lane & 15, hi = lane >> 4, l7 = lane & 7;
  for (int k0 = 0; k0 < K; k0 += 64) {
    __syncthreads();                       // previous compute done before overwrite
    stage64(A + k0, lda, lA, wave, lane);
    stage64(Wt + k0, ldw, lB, wave, lane);
    __syncthreads();                       // compiler drains vmcnt before barrier
#pragma unroll
    for (int ks = 0; ks < 2; ++ks) {
      short8_t a8[4], b8[4];
      const int sl = ks * 4 + hi;          // logical 16B slot 0..7
#pragma unroll
      for (int m = 0; m < 4; ++m) {
        const int r = wr * 64 + m * 16 + lm;
        a8[m] = *reinterpret_cast<const short8_t*>(lA + r * 64 + ((sl ^ l7) << 3));
      }
#pragma unroll
      for (int n = 0; n < 4; ++n) {
        const int r = wc * 64 + n * 16 + lm;
        b8[n] = *reinterpret_cast<const short8_t*>(lB + r * 64 + ((sl ^ l7) << 3));
      }
#pragma unroll
      for (int m = 0; m < 4; ++m)
#pragma unroll
        for (int n = 0; n < 4; ++n)
          acc[m][n] = __builtin_amdgcn_mfma_f32_16x16x32_bf16(a8[m], b8[n], acc[m][n], 0, 0, 0);
    }
  }
}

// mega_k: G1+G2+G3 in one dispatch (independent GEMMs; removes 2 launch gaps
// and 2 ramp-down tails; long-K G1 segment first for load balance).
//   [0,2048):    G1  [x|state]@[Wr|Wu], K=2048 -> rs=sig(v+br)*st, u=sig(v+bu)
//   [2048,4096): G2  x@[W1|Wc_top],     K=1024 -> sem=relu(v+b1)->SN, cx=v+bc
//   [4096,5120): G3  neighbors@W2,      K=1024 -> nei=relu(v+b2)->SN+1024
__global__ void mega_k(const __hip_bfloat16* __restrict__ A1,
                       const __hip_bfloat16* __restrict__ NB,
                       const __hip_bfloat16* __restrict__ Wru,
                       const __hip_bfloat16* __restrict__ W1cx,
                       const __hip_bfloat16* __restrict__ W2t,
                       const float* __restrict__ br, const float* __restrict__ bu,
                       const float* __restrict__ b1, const float* __restrict__ bc,
                       const float* __restrict__ b2,
                       __hip_bfloat16* __restrict__ RS, __hip_bfloat16* __restrict__ Ub,
                       __hip_bfloat16* __restrict__ SN, __hip_bfloat16* __restrict__ CXb) {
  __shared__ __hip_bfloat16 lA[128 * 64], lB[128 * 64];
  const int bid = blockIdx.x;
  const __hip_bfloat16 *A, *Wt;
  long lda, ldw;
  int K, nbx, epi, local, seg;
  if (bid < 2048)      { local = bid;        seg = 2048; epi = 0; A = A1; lda = 2048; Wt = Wru;  ldw = 2048; K = 2048; nbx = 16; }
  else if (bid < 4096) { local = bid - 2048; seg = 2048; epi = 1; A = A1; lda = 2048; Wt = W1cx; ldw = 1024; K = 1024; nbx = 16; }
  else                 { local = bid - 4096; seg = 1024; epi = 2; A = NB; lda = 1024; Wt = W2t;  ldw = 1024; K = 1024; nbx = 8;  }
  // segment bases are multiples of 8, so local%8 == global bid%8 == XCD id
  const int wg = xcd_map(local, seg);
  const long mBase = (long)(wg / nbx) * 128;
  const long nBase = (long)(wg % nbx) * 128;

  f32x4 acc[4][4];
#pragma unroll
  for (int m = 0; m < 4; ++m)
#pragma unroll
    for (int n = 0; n < 4; ++n) acc[m][n] = (f32x4){0.f, 0.f, 0.f, 0.f};

  gemm_acc(A + mBase * lda, lda, Wt + nBase * ldw, ldw, K, lA, lB, acc);

  const int tid = threadIdx.x, wave = tid >> 6, lane = tid & 63;
  const int wr = wave >> 1, wc = wave & 1, lm = lane & 15, hi = lane >> 4;
  const int row0 = (int)mBase + wr * 64 + hi * 4;
  const int col0 = (int)nBase + wc * 64 + lm;
#pragma unroll
  for (int m = 0; m < 4; ++m)
#pragma unroll
    for (int n = 0; n < 4; ++n)
#pragma unroll
      for (int j = 0; j < 4; ++j) {
        const long row = row0 + m * 16 + j;
        const int col = col0 + n * 16;
        const float v = acc[m][n][j];
        if (epi == 0) {
          if (col < HIDc) {
            float rr = sigf(v + br[col]);
            float st = __bfloat162float(A1[row * 2048 + 1024 + col]);
            RS[row * HIDc + col] = __float2bfloat16(rr * st);
          } else {
            int c = col - HIDc;
            Ub[row * HIDc + c] = __float2bfloat16(sigf(v + bu[c]));
          }
        } else if (epi == 1) {
          if (col < HIDc) {
            SN[row * 2048 + col] = __float2bfloat16(fmaxf(v + b1[col], 0.f));
          } else {
            int c = col - HIDc;
            CXb[row * HIDc + c] = __float2bfloat16(v + bc[c]);
          }
        } else {
          SN[row * 2048 + HIDc + col] = __float2bfloat16(fmaxf(v + b2[col], 0.f));
        }
      }
}

// final_c: cb = tanh(cx + rs @ Wc_bot^T) -> CB (bf16).
__global__ void final_c(const __hip_bfloat16* __restrict__ A, long lda,
                        const __hip_bfloat16* __restrict__ Wt, long ldw, int K, int nbx,
                        const __hip_bfloat16* __restrict__ auxbf,  // CXb (ld 1024)
                        __hip_bfloat16* __restrict__ out0) {
  __shared__ __hip_bfloat16 lA[128 * 64], lB[128 * 64];
  f32x4 acc[4][4];
#pragma unroll
  for (int m = 0; m < 4; ++m)
#pragma unroll
    for (int n = 0; n < 4; ++n) acc[m][n] = (f32x4){0.f, 0.f, 0.f, 0.f};

  const int wg = xcd_map(blockIdx.x, gridDim.x);
  const long mBase = (long)(wg / nbx) * 128;
  const long nBase = (long)(wg % nbx) * 128;
  gemm_acc(A + mBase * lda, lda, Wt + nBase * ldw, ldw, K, lA, lB, acc);

  const int tid = threadIdx.x, wave = tid >> 6, lane = tid & 63;
  const int wr = wave >> 1, wc = wave & 1, lm = lane & 15, hi = lane >> 4;
  const int row0 = (int)mBase + wr * 64 + hi * 4;
  const int col0 = (int)nBase + wc * 64 + lm;
#pragma unroll
  for (int m = 0; m < 4; ++m)
#pragma unroll
    for (int n = 0; n < 4; ++n)
#pragma unroll
      for (int j = 0; j < 4; ++j) {
        const long row = row0 + m * 16 + j;
        const int col = col0 + n * 16;
        const long idx = row * HIDc + col;
        float cb = tanh_fast(acc[m][n][j] + __bfloat162float(auxbf[idx]));
        out0[idx] = __float2bfloat16(cb);
      }
}

// final_g: accG = [sem|nei] @ Wg^T (K=2048);
// out = u*state + (1-u)*cb*sigmoid(accG+bg).
__global__ void final_g(const __hip_bfloat16* __restrict__ SN,
                        const __hip_bfloat16* __restrict__ Wgt,
                        const __hip_bfloat16* __restrict__ CB,
                        const __hip_bfloat16* __restrict__ U,
                        const __hip_bfloat16* __restrict__ stbf,  // A1 (state at col 1024+)
                        const float* __restrict__ bg,
                        float* __restrict__ out, int nbx) {
  __shared__ __hip_bfloat16 lA[128 * 64], lB[128 * 64];
  f32x4 acc[4][4];
#pragma unroll
  for (int m = 0; m < 4; ++m)
#pragma unroll
    for (int n = 0; n < 4; ++n) acc[m][n] = (f32x4){0.f, 0.f, 0.f, 0.f};

  const int wg = xcd_map(blockIdx.x, gridDim.x);
  const long mBase = (long)(wg / nbx) * 128;
  const long nBase = (long)(wg % nbx) * 128;
  gemm_acc(SN + mBase * 2048, 2048, Wgt + nBase * 2048, 2048, 2048, lA, lB, acc);

  const int tid = threadIdx.x, wave = tid >> 6, lane = tid & 63;
  const int wr = wave >> 1, wc = wave & 1, lm = lane & 15, hi = lane >> 4;
  const int row0 = (int)mBase + wr * 64 + hi * 4;
  const int col0 = (int)nBase + wc * 64 + lm;
#pragma unroll
  for (int m = 0; m < 4; ++m)
#pragma unroll
    for (int n = 0; n < 4; ++n)
#pragma unroll
      for (int j = 0; j < 4; ++j) {
        const long row = row0 + m * 16 + j;
        const int col = col0 + n * 16;
        const long idx = row * HIDc + col;
        float g = sigf(acc[m][n][j] + bg[col]);
        float u = __bfloat162float(U[idx]);
        float cb = __bfloat162float(CB[idx]);
        float st = __bfloat162float(stbf[row * 2048 + 1024 + col]);
        out[idx] = u * st + (1.f - u) * cb * g;
      }
}

// One prep kernel (proven r7): blocks [0,10240) transpose all 7 weight views
// to (N,K) bf16; blocks [10240,12288) pack activations to bf16.
__global__ __launch_bounds__(256)
void prep_k(const float4* __restrict__ in4, const float4* __restrict__ st4,
            __hip_bfloat16* __restrict__ A1, __hip_bfloat16* __restrict__ NB,
            const float* __restrict__ Wr, const float* __restrict__ Wu,
            const float* __restrict__ W1, const float* __restrict__ Wc,
            const float* __restrict__ W2, const float* __restrict__ Wg,
            __hip_bfloat16* __restrict__ Wru_t, __hip_bfloat16* __restrict__ W1cx_t,
            __hip_bfloat16* __restrict__ Wcb_t, __hip_bfloat16* __restrict__ W2_t,
            __hip_bfloat16* __restrict__ Wg_t) {
  const int bid = blockIdx.x;
  if (bid < 10240) {
    const float* s_; __hip_bfloat16* d_; long ldo; int j, ktiles;
    if (bid < 2048)      { j = bid;        s_ = Wr; d_ = Wru_t;               ldo = 2048; ktiles = 64; }
    else if (bid < 4096) { j = bid - 2048; s_ = Wu; d_ = Wru_t + 1024L * 2048; ldo = 2048; ktiles = 64; }
    else if (bid < 5120) { j = bid - 4096; s_ = W1; d_ = W1cx_t;              ldo = 1024; ktiles = 32; }
    else if (bid < 6144) { j = bid - 5120; s_ = Wc; d_ = W1cx_t + 1024L * 1024; ldo = 1024; ktiles = 32; }
    else if (bid < 7168) { j = bid - 6144; s_ = Wc + 1024L * 1024; d_ = Wcb_t; ldo = 1024; ktiles = 32; }
    else if (bid < 8192) { j = bid - 7168; s_ = W2; d_ = W2_t;                ldo = 1024; ktiles = 32; }
    else                 { j = bid - 8192; s_ = Wg; d_ = Wg_t;                ldo = 2048; ktiles = 64; }
    const int k0 = (j % ktiles) * 32, n0 = (j / ktiles) * 32;
    __shared__ float t[32][33];
    const int tx = threadIdx.x & 31, ty = threadIdx.x >> 5;
#pragma unroll
    for (int dy = 0; dy < 32; dy += 8)
      t[ty + dy][tx] = s_[(long)(k0 + ty + dy) * 1024 + n0 + tx];
    __syncthreads();
#pragma unroll
    for (int dy = 0; dy < 32; dy += 8)
      d_[(long)(n0 + ty + dy) * ldo + k0 + tx] = __float2bfloat16(t[tx][ty + dy]);
  } else {
    const long NI4 = (long)Bsz * 2048 / 4;
    const long NS4 = (long)Bsz * 1024 / 4;
    for (long i = (long)(bid - 10240) * 256 + threadIdx.x; i < NI4 + NS4;
         i += 2048L * 256) {
      float4 v;
      __hip_bfloat16* dst;
      if (i < NI4) {
        v = in4[i];
        long e = i << 2;
        long row = e >> 11;
        int col = (int)(e & 2047);
        dst = (col < 1024) ? (A1 + row * 2048 + col) : (NB + row * 1024 + (col - 1024));
      } else {
        long jj = i - NI4;
        v = st4[jj];
        long e = jj << 2;
        long row = e >> 10;
        int col = (int)(e & 1023);
        dst = A1 + row * 2048 + 1024 + col;
      }
      union { __hip_bfloat16 h[4]; s16x4 s; } u;
      u.h[0] = __float2bfloat16(v.x);
      u.h[1] = __float2bfloat16(v.y);
      u.h[2] = __float2bfloat16(v.z);
      u.h[3] = __float2bfloat16(v.w);
      *reinterpret_cast<s16x4*>(dst) = u.s;
    }
  }
}

extern "C" void kernel_launch(void* const* d_in, const int* in_sizes, int n_in,
                              void* d_out, int out_size, void* d_ws, size_t ws_size,
                              hipStream_t stream) {
  const float* inputs = (const float*)d_in[0];
  const float* state = (const float*)d_in[1];
  const float* Wr = (const float*)d_in[2];
  const float* br = (const float*)d_in[3];
  const float* Wu = (const float*)d_in[4];
  const float* bu = (const float*)d_in[5];
  const float* Wc = (const float*)d_in[6];
  const float* bc = (const float*)d_in[7];
  const float* W1 = (const float*)d_in[8];
  const float* b1 = (const float*)d_in[9];
  const float* W2 = (const float*)d_in[10];
  const float* b2 = (const float*)d_in[11];
  const float* Wg = (const float*)d_in[12];
  const float* bg = (const float*)d_in[13];
  float* out = (float*)d_out;

  char* ws = (char*)d_ws;
  __hip_bfloat16* A1    = (__hip_bfloat16*)(ws);                 // 64 MB [x|state]
  __hip_bfloat16* NB    = (__hip_bfloat16*)(ws + 67108864L);     // 32 MB neighbors -> CB
  __hip_bfloat16* RS    = (__hip_bfloat16*)(ws + 100663296L);    // 32 MB r*state
  __hip_bfloat16* Ub    = (__hip_bfloat16*)(ws + 134217728L);    // 32 MB u
  __hip_bfloat16* SN    = (__hip_bfloat16*)(ws + 167772160L);    // 64 MB [sem|nei]
  __hip_bfloat16* CXb   = (__hip_bfloat16*)(ws + 234881024L);    // 32 MB x@Wc_top+bc
  __hip_bfloat16* Wru_t = (__hip_bfloat16*)(ws + 268435456L);    // 8 MB  (2048 x 2048)
  __hip_bfloat16* W1cx_t= (__hip_bfloat16*)(ws + 276824064L);    // 4 MB  (2048 x 1024)
  __hip_bfloat16* Wcb_t = (__hip_bfloat16*)(ws + 281018368L);    // 2 MB  (1024 x 1024)
  __hip_bfloat16* W2_t  = (__hip_bfloat16*)(ws + 283115520L);    // 2 MB  (1024 x 1024)
  __hip_bfloat16* Wg_t  = (__hip_bfloat16*)(ws + 285212672L);    // 4 MB  (1024 x 2048)
  __hip_bfloat16* CB    = NB;   // NB dead after mega (G3 segment); reuse for tanh(c)

  prep_k<<<12288, 256, 0, stream>>>((const float4*)inputs, (const float4*)state,
                                    A1, NB, Wr, Wu, W1, Wc, W2, Wg,
                                    Wru_t, W1cx_t, Wcb_t, W2_t, Wg_t);

  // G1 + G2 + G3 fused into one dispatch (5120 blocks).
  mega_k<<<5120, 256, 0, stream>>>(A1, NB, Wru_t, W1cx_t, W2_t,
                                   br, bu, b1, bc, b2,
                                   RS, Ub, SN, CXb);

  // final_c: cb = tanh(cx + rs @ Wc_bot^T) -> CB
  final_c<<<1024, 256, 0, stream>>>(RS, 1024, Wcb_t, 1024, 1024, 8, CXb, CB);

  // final_g: out = u*state + (1-u)*cb*sigmoid([sem|nei] @ Wg^T + bg)
  final_g<<<1024, 256, 0, stream>>>(SN, Wg_t, CB, Ub, A1, bg, out, 8);
}